// Round 2
// baseline (443.836 us; speedup 1.0000x reference)
//
#include <hip/hip_runtime.h>

// Problem constants (match reference)
#define BB    32
#define HH    224
#define WW    224
#define OUTC  64
#define KK    5
#define PADP  2
#define LL    (HH * WW)            // 50176
#define GPB   (LL / 4)             // 12544 groups of 4 positions per image

__global__ __launch_bounds__(256) void gray_conv_kernel(
    const float* __restrict__ x,     // [B, 1, H, W]
    const float* __restrict__ wgt,   // [OUT, 25]
    float* __restrict__ out)         // [B, OUT, H, W]
{
    // Only |w|^2 lives in LDS (64 floats, one ds_read_b32 broadcast per o).
    // The weight rows themselves are read per-o straight from the kernel arg:
    // the address is wave-uniform (uniform pointer + uniform loop index), so
    // the backend scalarizes them into s_load_dwordx8 -> SGPRs. FMAs then
    // consume the weight as the (single allowed) SGPR operand of v_fmac_f32,
    // keeping the LDS pipe and lgkm latency off the critical path.
    __shared__ float sw2[OUTC];

    const int tid = threadIdx.x;

    if (tid < OUTC) {
        float s = 0.f;
        #pragma unroll
        for (int d = 0; d < 25; ++d) {
            const float v = wgt[tid * 25 + d];
            s = fmaf(v, v, s);
        }
        sw2[tid] = s;
    }
    __syncthreads();

    // Each thread owns 4 consecutive positions in one row (4 | 224, so a
    // group never crosses a row). Block covers 1024 consecutive positions.
    const int g   = blockIdx.x * 256 + tid;   // group index, 0 .. B*L/4-1
    const int b   = g / GPB;
    const int gr  = g - b * GPB;
    const int rem = gr * 4;                   // first of 4 positions
    const int h   = rem / WW;
    const int w0  = rem - h * WW;             // multiple of 4

    const float* xb = x + (size_t)b * LL;

    // 5x8 patch covering columns w0-2 .. w0+5 (all 4 positions' taps).
    // Branchless: clamp address into bounds (always-valid load), mask to 0.
    int  xc[8];
    bool okc[8];
    #pragma unroll
    for (int c = 0; c < 8; ++c) {
        const int xx = w0 + c - PADP;
        xc[c]  = min(max(xx, 0), WW - 1);
        okc[c] = (unsigned)xx < (unsigned)WW;
    }

    float p[5][8];
    #pragma unroll
    for (int r = 0; r < KK; ++r) {
        const int  yy  = h + r - PADP;
        const int  yc  = min(max(yy, 0), HH - 1);
        const bool okr = (unsigned)yy < (unsigned)HH;
        const float* xrow = xb + yc * WW;
        #pragma unroll
        for (int c = 0; c < 8; ++c) {
            float v = xrow[xc[c]];
            p[r][c] = (okr && okc[c]) ? v : 0.f;
        }
    }

    // |x|^2 per position via shared per-column squared sums: 40 FMA + 16 add
    // instead of 100 FMA.
    float colsq[8];
    #pragma unroll
    for (int c = 0; c < 8; ++c) {
        float s = 0.f;
        #pragma unroll
        for (int r = 0; r < KK; ++r) s = fmaf(p[r][c], p[r][c], s);
        colsq[c] = s;
    }
    float x2[4];
    #pragma unroll
    for (int j = 0; j < 4; ++j) {
        x2[j] = ((colsq[j] + colsq[j + 1]) + (colsq[j + 2] + colsq[j + 3]))
                + colsq[j + 4];
    }

    float* ob = out + (size_t)b * OUTC * LL + rem;

    // unroll 2: double-buffers the scalar weight-row loads (2x25 SGPRs) so
    // row o+1's s_loads pipeline under row o's FMAs without blowing the
    // SGPR budget.
    #pragma unroll 2
    for (int o = 0; o < OUTC; ++o) {
        const float* wrow = wgt + o * 25;    // wave-uniform -> s_load
        float wv[25];
        #pragma unroll
        for (int d = 0; d < 25; ++d) wv[d] = wrow[d];
        const float w2 = sw2[o];             // ds_read_b32 broadcast

        // 4 independent 25-FMA dot chains -> ILP covers FMA latency.
        float dot[4];
        #pragma unroll
        for (int j = 0; j < 4; ++j) {
            float s = 0.f;
            #pragma unroll
            for (int r = 0; r < KK; ++r)
                #pragma unroll
                for (int k = 0; k < KK; ++k)
                    s = fmaf(p[r][j + k], wv[r * KK + k], s);
            dot[j] = s;
        }

        float r4[4];
        #pragma unroll
        for (int j = 0; j < 4; ++j) {
            float d2 = fmaf(-2.f, dot[j], x2[j] + w2);
            d2 = fmaxf(d2, 0.f);
            r4[j] = __builtin_amdgcn_sqrtf(d2);
        }
        // rem is a multiple of 4 and LL is a multiple of 4 -> 16B-aligned.
        *reinterpret_cast<float4*>(ob + (size_t)o * LL) =
            make_float4(r4[0], r4[1], r4[2], r4[3]);
    }
}

extern "C" void kernel_launch(void* const* d_in, const int* in_sizes, int n_in,
                              void* d_out, int out_size, void* d_ws, size_t ws_size,
                              hipStream_t stream) {
    const float* x   = (const float*)d_in[0];
    const float* wgt = (const float*)d_in[1];
    float* out       = (float*)d_out;

    const int groups = BB * GPB;                // 401,408 4-position groups
    const int blocks = groups / 256;            // 1568 blocks
    gray_conv_kernel<<<dim3(blocks), dim3(256), 0, stream>>>(x, wgt, out);
}

// Round 4
// 429.087 us; speedup vs baseline: 1.0344x; 1.0344x over previous
//
#include <hip/hip_runtime.h>

// Problem constants (match reference)
#define BB    32
#define HH    224
#define WW    224
#define OUTC  64
#define KK    5
#define PADP  2
#define LL    (HH * WW)            // 50176
#define GPB   (LL / 4)             // 12544 groups of 4 positions per image

// LDS input tile: block covers 1024 consecutive positions (<= 6 image rows);
// patch needs rows h0-2 .. h_last+2 <= h0+7  -> 10 rows, width 224 + 2+2 pad.
#define SROWS 10
#define SCOLS 228

typedef float f4 __attribute__((ext_vector_type(4)));

__global__ __launch_bounds__(256) void gray_conv_kernel(
    const float* __restrict__ x,     // [B, 1, H, W]
    const float* __restrict__ wgt,   // [OUT, 25]
    float* __restrict__ out)         // [B, OUT, H, W]
{
    __shared__ float sx[SROWS * SCOLS];   // zero-padded input rows (9.1 KB)
    __shared__ float sw2[OUTC];

    const int tid = threadIdx.x;

    // ---- block geometry (whole block lives in one image: 1024 | LL) ----
    const int g0   = blockIdx.x * 256;        // first group of this block
    const int b    = g0 / GPB;
    const int gr0  = g0 - b * GPB;
    const int rem0 = gr0 * 4;                 // first position in image
    const int h0   = rem0 / WW;               // first output row touched

    const float* xb = x + (size_t)b * LL;

    // ---- stage zero-padded input rows h0-2 .. h0+7 into LDS (coalesced) ----
    for (int i = tid; i < SROWS * SCOLS; i += 256) {
        const int r    = i / SCOLS;
        const int c    = i - r * SCOLS;
        const int grow = h0 - PADP + r;
        const int gcol = c - PADP;
        float v = 0.f;
        if ((unsigned)grow < (unsigned)HH && (unsigned)gcol < (unsigned)WW)
            v = xb[grow * WW + gcol];
        sx[i] = v;
    }

    // |w|^2 per filter (tiny, once per block)
    if (tid < OUTC) {
        float s = 0.f;
        #pragma unroll
        for (int d = 0; d < 25; ++d) {
            const float v = wgt[tid * 25 + d];
            s = fmaf(v, v, s);
        }
        sw2[tid] = s;
    }
    __syncthreads();

    // ---- per-thread: 4 consecutive positions in one row (4 | 224) ----
    const int g   = g0 + tid;
    const int gr  = g - b * GPB;
    const int rem = gr * 4;
    const int h   = rem / WW;
    const int w0  = rem - h * WW;             // multiple of 4
    const int hl  = h - h0;                   // 0..5

    // Patch taps straight from LDS, no clamping needed (pad materialized).
    // p[r][c] corresponds to global (h + r - 2, w0 + c - 2).
    const float* ps = sx + hl * SCOLS + w0;
    float p[5][8];
    #pragma unroll
    for (int r = 0; r < KK; ++r)
        #pragma unroll
        for (int c = 0; c < 8; ++c)
            p[r][c] = ps[r * SCOLS + c];

    // |x|^2 per position via shared per-column squared sums.
    float colsq[8];
    #pragma unroll
    for (int c = 0; c < 8; ++c) {
        float s = 0.f;
        #pragma unroll
        for (int r = 0; r < KK; ++r) s = fmaf(p[r][c], p[r][c], s);
        colsq[c] = s;
    }
    float x2[4];
    #pragma unroll
    for (int j = 0; j < 4; ++j) {
        x2[j] = ((colsq[j] + colsq[j + 1]) + (colsq[j + 2] + colsq[j + 3]))
                + colsq[j + 4];
    }

    float* ob = out + (size_t)b * OUTC * LL + rem;

    // Weight rows read scalar (wave-uniform -> s_load). unroll 2 pipelines
    // next row's s_loads under current row's FMAs.
    #pragma unroll 2
    for (int o = 0; o < OUTC; ++o) {
        const float* wrow = wgt + o * 25;
        const float  w2   = sw2[o];

        float dot[4] = {0.f, 0.f, 0.f, 0.f};
        #pragma unroll
        for (int r = 0; r < KK; ++r)
            #pragma unroll
            for (int k = 0; k < KK; ++k) {
                const float wv = wrow[r * KK + k];
                #pragma unroll
                for (int j = 0; j < 4; ++j)
                    dot[j] = fmaf(p[r][j + k], wv, dot[j]);
            }

        f4 r4;
        #pragma unroll
        for (int j = 0; j < 4; ++j) {
            float d2 = fmaf(-2.f, dot[j], x2[j] + w2);
            d2 = fmaxf(d2, 0.f);
            r4[j] = __builtin_amdgcn_sqrtf(d2);
        }
        // Output is write-once; keep it out of L2 (nt store). 16B-aligned.
        __builtin_nontemporal_store(r4, (f4*)(ob + (size_t)o * LL));
    }
}

extern "C" void kernel_launch(void* const* d_in, const int* in_sizes, int n_in,
                              void* d_out, int out_size, void* d_ws, size_t ws_size,
                              hipStream_t stream) {
    const float* x   = (const float*)d_in[0];
    const float* wgt = (const float*)d_in[1];
    float* out       = (float*)d_out;

    const int groups = BB * GPB;                // 401,408 4-position groups
    const int blocks = groups / 256;            // 1568 blocks
    gray_conv_kernel<<<dim3(blocks), dim3(256), 0, stream>>>(x, wgt, out);
}

// Round 5
// 425.663 us; speedup vs baseline: 1.0427x; 1.0080x over previous
//
#include <hip/hip_runtime.h>

// Problem constants (match reference)
#define BB    32
#define HH    224
#define WW    224
#define OUTC  64
#define KK    5
#define PADP  2
#define LL    (HH * WW)            // 50176
#define GPB2  (LL / 2)             // 25088 groups of 2 positions per image

// Block covers 512 consecutive positions (<= 4 image rows; start col <= 192,
// 192+511 < 4*224). Patch needs rows h0-2 .. h_last+2 <= h0+5 -> 8 rows.
#define SROWS 8
#define SCOLS 228

typedef float f2 __attribute__((ext_vector_type(2)));

// 2 positions/thread keeps live VGPRs ~55 -> with (256,8) launch bounds the
// compiler targets <=64 VGPR => 8 resident waves/SIMD (was ~4 in the 65-128
// band with 4 positions/thread). Grid doubles to 3136 blocks. This is the
// occupancy/latency experiment; load/store structure unchanged from r4.
__global__ __launch_bounds__(256, 8) void gray_conv_kernel(
    const float* __restrict__ x,     // [B, 1, H, W]
    const float* __restrict__ wgt,   // [OUT, 25]
    float* __restrict__ out)         // [B, OUT, H, W]
{
    __shared__ float sx[SROWS * SCOLS];   // zero-padded input rows (7.3 KB)
    __shared__ float sw2[OUTC];

    const int tid = threadIdx.x;

    // ---- block geometry (whole block lives in one image: 512 | LL) ----
    const int g0   = blockIdx.x * 256;        // first group of this block
    const int b    = g0 / GPB2;
    const int gr0  = g0 - b * GPB2;
    const int rem0 = gr0 * 2;                 // first position in image
    const int h0   = rem0 / WW;               // first output row touched

    const float* xb = x + (size_t)b * LL;

    // ---- stage zero-padded input rows h0-2 .. h0+5 into LDS (coalesced) ----
    for (int i = tid; i < SROWS * SCOLS; i += 256) {
        const int r    = i / SCOLS;
        const int c    = i - r * SCOLS;
        const int grow = h0 - PADP + r;
        const int gcol = c - PADP;
        float v = 0.f;
        if ((unsigned)grow < (unsigned)HH && (unsigned)gcol < (unsigned)WW)
            v = xb[grow * WW + gcol];
        sx[i] = v;
    }

    // |w|^2 per filter (tiny, once per block)
    if (tid < OUTC) {
        float s = 0.f;
        #pragma unroll
        for (int d = 0; d < 25; ++d) {
            const float v = wgt[tid * 25 + d];
            s = fmaf(v, v, s);
        }
        sw2[tid] = s;
    }
    __syncthreads();

    // ---- per-thread: 2 consecutive positions in one row (2 | 224) ----
    const int g   = g0 + tid;
    const int gr  = g - b * GPB2;
    const int rem = gr * 2;
    const int h   = rem / WW;
    const int w0  = rem - h * WW;             // even
    const int hl  = h - h0;                   // 0..3

    // Patch taps from LDS, no clamping (pad materialized).
    // p[r][c] corresponds to global (h + r - 2, w0 + c - 2).
    const float* ps = sx + hl * SCOLS + w0;
    float p[5][6];
    #pragma unroll
    for (int r = 0; r < KK; ++r)
        #pragma unroll
        for (int c = 0; c < 6; ++c)
            p[r][c] = ps[r * SCOLS + c];

    // |x|^2 per position via per-column squared sums.
    float colsq[6];
    #pragma unroll
    for (int c = 0; c < 6; ++c) {
        float s = 0.f;
        #pragma unroll
        for (int r = 0; r < KK; ++r) s = fmaf(p[r][c], p[r][c], s);
        colsq[c] = s;
    }
    float x2[2];
    #pragma unroll
    for (int j = 0; j < 2; ++j) {
        x2[j] = ((colsq[j] + colsq[j + 1]) + (colsq[j + 2] + colsq[j + 3]))
                + colsq[j + 4];
    }

    float* ob = out + (size_t)b * OUTC * LL + rem;

    // Weight rows read scalar (wave-uniform -> s_load). unroll 2 pipelines
    // next row's s_loads under current row's FMAs.
    #pragma unroll 2
    for (int o = 0; o < OUTC; ++o) {
        const float* wrow = wgt + o * 25;
        const float  w2   = sw2[o];

        float dot[2] = {0.f, 0.f};
        #pragma unroll
        for (int r = 0; r < KK; ++r)
            #pragma unroll
            for (int k = 0; k < KK; ++k) {
                const float wv = wrow[r * KK + k];
                #pragma unroll
                for (int j = 0; j < 2; ++j)
                    dot[j] = fmaf(p[r][j + k], wv, dot[j]);
            }

        f2 r2;
        #pragma unroll
        for (int j = 0; j < 2; ++j) {
            float d2 = fmaf(-2.f, dot[j], x2[j] + w2);
            d2 = fmaxf(d2, 0.f);
            r2[j] = __builtin_amdgcn_sqrtf(d2);
        }
        // rem even -> 8B-aligned. Write-once data: nontemporal.
        __builtin_nontemporal_store(r2, (f2*)(ob + (size_t)o * LL));
    }
}

extern "C" void kernel_launch(void* const* d_in, const int* in_sizes, int n_in,
                              void* d_out, int out_size, void* d_ws, size_t ws_size,
                              hipStream_t stream) {
    const float* x   = (const float*)d_in[0];
    const float* wgt = (const float*)d_in[1];
    float* out       = (float*)d_out;

    const int groups = BB * GPB2;               // 802,816 2-position groups
    const int blocks = groups / 256;            // 3136 blocks
    gray_conv_kernel<<<dim3(blocks), dim3(256), 0, stream>>>(x, wgt, out);
}